// Round 9
// baseline (627.603 us; speedup 1.0000x reference)
//
#include <hip/hip_runtime.h>

#define B_ 2
#define N_ 20000
#define C_ 256
#define K_ 16
#define H_ 128
#define ROWS (B_ * N_)       // 40000
#define MT 313               // ceil(40000/128)
#define MPAD (MT * 128)      // 40064

typedef __attribute__((ext_vector_type(8))) short bf16x8;
typedef __attribute__((ext_vector_type(4))) float f32x4;

__device__ __forceinline__ float us2f(unsigned short u) {
    return __uint_as_float(((unsigned int)u) << 16);
}
__device__ __forceinline__ unsigned short f2us(float f) {
    unsigned int u = __float_as_uint(f);
    unsigned int r = (u + 0x7fffu + ((u >> 16) & 1u)) >> 16;
    return (unsigned short)r;
}
__device__ __forceinline__ float wred(float v) {
#pragma unroll
    for (int off = 32; off > 0; off >>= 1) v += __shfl_xor(v, off, 64);
    return v;
}
__device__ __forceinline__ void gld_lds16(const unsigned short* g, unsigned short* l) {
    __builtin_amdgcn_global_load_lds(
        (__attribute__((address_space(1))) void*)(g),
        (__attribute__((address_space(3))) void*)(l), 16, 0, 0);
}

// ---------------- batched fp32 -> bf16 convert: x3 + x0/x1/x2 ----------------
extern "C" __global__ void __launch_bounds__(256)
cvtx_kernel(const float* __restrict__ x3, const float* __restrict__ x0,
            const float* __restrict__ x1, const float* __restrict__ x2,
            unsigned short* __restrict__ d3, unsigned short* __restrict__ dq, int n4) {
    const int y = blockIdx.y;
    const float* src = (y == 0) ? x3 : (y == 1 ? x0 : (y == 2 ? x1 : x2));
    unsigned short* dst = (y == 0) ? d3 : (dq + (size_t)(y - 1) * MPAD * C_);
    int t = blockIdx.x * 256 + threadIdx.x;
    if (t >= n4) return;
    float4 v = ((const float4*)src)[t];
    ushort4 o;
    o.x = f2us(v.x); o.y = f2us(v.y); o.z = f2us(v.z); o.w = f2us(v.w);
    ((ushort4*)dst)[t] = o;
}

// ---------------- batched weight convert (4 tensors, one dispatch) -----------
extern "C" __global__ void __launch_bounds__(256)
cvtw_kernel(const float* __restrict__ s0, const float* __restrict__ s1,
            const float* __restrict__ s2, const float* __restrict__ s3,
            unsigned short* __restrict__ d0, unsigned short* __restrict__ d1,
            unsigned short* __restrict__ d2, unsigned short* __restrict__ d3) {
    const int y = blockIdx.y;
    const float* src = (y == 0) ? s0 : (y == 1 ? s1 : (y == 2 ? s2 : s3));
    unsigned short* dst = (y == 0) ? d0 : (y == 1 ? d1 : (y == 2 ? d2 : d3));
    const int n4 = (y < 3) ? (3 * C_ * C_ / 4) : (H_ * C_ / 4);
    int t = blockIdx.x * 256 + threadIdx.x;
    if (t >= n4) return;
    float4 v = ((const float4*)src)[t];
    ushort4 o;
    o.x = f2us(v.x); o.y = f2us(v.y); o.z = f2us(v.z); o.w = f2us(v.w);
    ((ushort4*)dst)[t] = o;
}

// ---------------- shared 128x128 MFMA tile body (BK=64) ----------------------
// vs round-8 body: K-step widened 32->64 (half the barrier drains; 4 K-steps
// for K=256). LDS [128][64] per matrix (32 KB total). 16B-slot XOR swizzle
// widened to ^((row>>1)&7): full 32-bank spread (2-way, free). Swizzle applied
// on global SOURCE chunk during staging (LDS dest linear, as global_load_lds
// requires) and on the ds_read address — both sides, same involution.
// Epilogue: operand-swapped mfma(b,a) -> lane holds row x 4 consecutive cols
// -> packed 8B uint2 stores (verified round 8, absmax 0.03125).
__device__ __forceinline__ void gemm_tile_body(
    const unsigned short* __restrict__ A, const unsigned short* __restrict__ W,
    const float* __restrict__ bias, unsigned short* __restrict__ O,
    const int m0, const int n0, const int ldo) {
    const int tid = threadIdx.x;
    const int w = tid >> 6, lane = tid & 63;
    const int l15 = lane & 15, l4 = lane >> 4;
    const int rowq = (w >> 1) * 64;   // wave quadrant (m side)
    const int colq = (w & 1) * 64;    // wave quadrant (n side)

    __shared__ unsigned short As[128 * 64];
    __shared__ unsigned short Bs[128 * 64];

    f32x4 acc[4][4] = {};

    const int srow = w * 8 + (lane >> 3);    // staging row within 32-row group
    const int schunk = lane & 7;             // 16B chunk index within 128B row

    for (int k0 = 0; k0 < 256; k0 += 64) {
        __syncthreads();
#pragma unroll
        for (int issue = 0; issue < 4; ++issue) {
            const int lrow = issue * 32 + srow;                  // LDS-local row
            const int sc = (schunk ^ ((lrow >> 1) & 7)) * 8;     // swizzled src chunk
            gld_lds16(A + (size_t)(m0 + lrow) * 256 + k0 + sc, As + issue * 2048 + w * 512);
            gld_lds16(W + (size_t)(n0 + lrow) * 256 + k0 + sc, Bs + issue * 2048 + w * 512);
        }
        __syncthreads();
#pragma unroll
        for (int ks = 0; ks < 2; ++ks) {
            bf16x8 a[4], b[4];
#pragma unroll
            for (int i = 0; i < 4; ++i) {
                const int ra = rowq + i * 16 + l15;
                const int ch = ((ks << 2) | l4) ^ ((ra >> 1) & 7);
                a[i] = *(const bf16x8*)&As[ra * 64 + ch * 8];
            }
#pragma unroll
            for (int j = 0; j < 4; ++j) {
                const int rb = colq + j * 16 + l15;
                const int ch = ((ks << 2) | l4) ^ ((rb >> 1) & 7);
                b[j] = *(const bf16x8*)&Bs[rb * 64 + ch * 8];
            }
#pragma unroll
            for (int i = 0; i < 4; ++i)
#pragma unroll
                for (int j = 0; j < 4; ++j)
                    acc[i][j] = __builtin_amdgcn_mfma_f32_16x16x32_bf16(b[j], a[i], acc[i][j], 0, 0, 0);
        }
    }

    // epilogue: lane holds row m0+rowq+i*16+l15, cols n0+colq+j*16+l4*4+[0,4)
#pragma unroll
    for (int i = 0; i < 4; ++i) {
        const int grow = m0 + rowq + i * 16 + l15;
        if (grow < ROWS) {
#pragma unroll
            for (int j = 0; j < 4; ++j) {
                const int gcol = n0 + colq + j * 16 + l4 * 4;
                const float4 b4 = *(const float4*)&bias[gcol];
                uint2 pk;
                pk.x = (unsigned int)f2us(acc[i][j][0] + b4.x) |
                       ((unsigned int)f2us(acc[i][j][1] + b4.y) << 16);
                pk.y = (unsigned int)f2us(acc[i][j][2] + b4.z) |
                       ((unsigned int)f2us(acc[i][j][3] + b4.w) << 16);
                *(uint2*)&O[(size_t)grow * ldo + gcol] = pk;
            }
        }
    }
}

// ---------------- merged KV GEMM: K0,V0,K1,V1,K2,V2; A = x3 for all ----------
// grid (12, MT): zi=panel>>1 (0..5): i=zi>>1, V if zi&1; n0=(panel&1)*128.
extern "C" __global__ void __launch_bounds__(256)
gemm_kv(const unsigned short* __restrict__ x3bf,
        const unsigned short* __restrict__ wk, const unsigned short* __restrict__ wv,
        const float* __restrict__ bk, const float* __restrict__ bv,
        unsigned short* __restrict__ kv) {
    const int panel = blockIdx.x;
    const int zi = panel >> 1;
    const int i = zi >> 1;
    const int isV = zi & 1;
    const unsigned short* W = (isV ? wv : wk) + (size_t)i * C_ * C_;
    const float* bias = (isV ? bv : bk) + i * C_;
    unsigned short* O = kv + (size_t)zi * MPAD * C_;
    gemm_tile_body(x3bf, W, bias, O, blockIdx.y * 128, (panel & 1) * 128, C_);
}

// ---------------- gate GEMM: H = x3 @ Wg1^T + bg1 (128 cols) -----------------
extern "C" __global__ void __launch_bounds__(256)
gemm_h(const unsigned short* __restrict__ x3bf, const unsigned short* __restrict__ wg1,
       const float* __restrict__ bg1, unsigned short* __restrict__ Hout) {
    gemm_tile_body(x3bf, wg1, bg1, Hout, blockIdx.x * 128, 0, H_);
}

// ---------------- Q GEMM: Q = xq[i] @ Wq[i]^T + bq[i] ------------------------
extern "C" __global__ void __launch_bounds__(256)
gemm_q(const unsigned short* __restrict__ A, const unsigned short* __restrict__ W,
       const float* __restrict__ bias, unsigned short* __restrict__ O) {
    gemm_tile_body(A, W, bias, O, blockIdx.x * 128, blockIdx.y * 128, C_);
}

// ---------------- gate stage 2: alpha = softmax(relu(H)@Wg2^T + bg2) ---------
extern "C" __global__ void __launch_bounds__(256)
gate2_kernel(const unsigned short* __restrict__ Hbf, const float* __restrict__ Wg2,
             const float* __restrict__ bg2, float* __restrict__ alpha) {
    const int tid = threadIdx.x;
    const int w = tid >> 6, lane = tid & 63;
    const int row = blockIdx.x * 4 + w;
    const float h0 = fmaxf(us2f(Hbf[(size_t)row * H_ + lane]), 0.f);
    const float h1 = fmaxf(us2f(Hbf[(size_t)row * H_ + 64 + lane]), 0.f);
    float lg[3];
#pragma unroll
    for (int l = 0; l < 3; ++l) {
        const float* w2 = Wg2 + l * H_;
        lg[l] = wred(h0 * w2[lane] + h1 * w2[lane + 64]) + bg2[l];
    }
    float m = fmaxf(lg[0], fmaxf(lg[1], lg[2]));
    float e0 = expf(lg[0] - m), e1 = expf(lg[1] - m), e2 = expf(lg[2] - m);
    float inv = 1.f / (e0 + e1 + e2);
    if (lane == 0) {
        alpha[row * 3 + 0] = e0 * inv;
        alpha[row * 3 + 1] = e1 * inv;
        alpha[row * 3 + 2] = e2 * inv;
    }
}

// ---------------- attention core (round-0 proven body, 96 VGPR) --------------
// 16 lanes per row, 4 rows per wave, 16 rows per block.
// lane t owns channels { j*64 + t*4 + [0,4) : j = 0..3 }.
__device__ __forceinline__ void attn_core(
    const unsigned short* __restrict__ q, const unsigned short* __restrict__ kf,
    const unsigned short* __restrict__ vf, const int* __restrict__ knn,
    const int row, const int b, const int n, const int t,
    float* __restrict__ qv, float* __restrict__ o) {
    const unsigned short* qp = q + (size_t)row * C_ + t * 4;
#pragma unroll
    for (int j = 0; j < 4; ++j) {
        ushort4 u = *(const ushort4*)(qp + j * 64);
        qv[j * 4 + 0] = us2f(u.x);
        qv[j * 4 + 1] = us2f(u.y);
        qv[j * 4 + 2] = us2f(u.z);
        qv[j * 4 + 3] = us2f(u.w);
    }

    int idxs[K_];
    float s[K_];
#pragma unroll
    for (int k = 0; k < K_; ++k) {
        idxs[k] = knn[n * K_ + k];
        const unsigned short* kp = kf + ((size_t)b * N_ + idxs[k]) * C_ + t * 4;
        float p = 0.f;
#pragma unroll
        for (int j = 0; j < 4; ++j) {
            ushort4 u = *(const ushort4*)(kp + j * 64);
            p += qv[j * 4 + 0] * us2f(u.x) + qv[j * 4 + 1] * us2f(u.y) +
                 qv[j * 4 + 2] * us2f(u.z) + qv[j * 4 + 3] * us2f(u.w);
        }
#pragma unroll
        for (int off = 1; off < 16; off <<= 1) p += __shfl_xor(p, off, 64);
        s[k] = p * 0.0625f;
    }

    float m = s[0];
#pragma unroll
    for (int k = 1; k < K_; ++k) m = fmaxf(m, s[k]);
    float sum = 0.f;
#pragma unroll
    for (int k = 0; k < K_; ++k) {
        s[k] = __expf(s[k] - m);
        sum += s[k];
    }
    const float inv = 1.f / sum;

#pragma unroll
    for (int c = 0; c < 16; ++c) o[c] = 0.f;
#pragma unroll
    for (int k = 0; k < K_; ++k) {
        const float a = s[k] * inv;
        const unsigned short* vp = vf + ((size_t)b * N_ + idxs[k]) * C_ + t * 4;
#pragma unroll
        for (int j = 0; j < 4; ++j) {
            ushort4 u = *(const ushort4*)(vp + j * 64);
            o[j * 4 + 0] += a * us2f(u.x);
            o[j * 4 + 1] += a * us2f(u.y);
            o[j * 4 + 2] += a * us2f(u.z);
            o[j * 4 + 3] += a * us2f(u.w);
        }
    }
}

// ---------------- i=0,1: attn + LN + alpha-weighted accumulate ---------------
extern "C" __global__ void __launch_bounds__(256)
attn_kernel(const unsigned short* __restrict__ q, const unsigned short* __restrict__ kf,
            const unsigned short* __restrict__ vf, const int* __restrict__ knn,
            const float* __restrict__ alpha, const float* __restrict__ lng,
            const float* __restrict__ lnb, float* __restrict__ accum, const int iblk) {
    const int tid = threadIdx.x;
    const int t = tid & 15;
    const int row = blockIdx.x * 16 + (tid >> 4);
    const int b = row / N_;
    const int n = row - b * N_;
    float qv[16], o[16];
    attn_core(q, kf, vf, knn, row, b, n, t, qv, o);

    float s1 = 0.f, s2 = 0.f;
#pragma unroll
    for (int c = 0; c < 16; ++c) {
        o[c] += qv[c];
        s1 += o[c];
        s2 += o[c] * o[c];
    }
#pragma unroll
    for (int off = 1; off < 16; off <<= 1) {
        s1 += __shfl_xor(s1, off, 64);
        s2 += __shfl_xor(s2, off, 64);
    }
    const float mean = s1 * (1.f / C_);
    const float var = s2 * (1.f / C_) - mean * mean;
    const float rstd = rsqrtf(var + 1e-5f);

    const float a = alpha[row * 3 + iblk];
    const float* gp = lng + iblk * C_ + t * 4;
    const float* bp = lnb + iblk * C_ + t * 4;
    float* ap = accum + (size_t)row * C_ + t * 4;
#pragma unroll
    for (int j = 0; j < 4; ++j) {
        float4 gg = *(const float4*)(gp + j * 64);
        float4 bb = *(const float4*)(bp + j * 64);
        float4 y;
        y.x = ((o[j * 4 + 0] - mean) * rstd * gg.x + bb.x) * a;
        y.y = ((o[j * 4 + 1] - mean) * rstd * gg.y + bb.y) * a;
        y.z = ((o[j * 4 + 2] - mean) * rstd * gg.z + bb.z) * a;
        y.w = ((o[j * 4 + 3] - mean) * rstd * gg.w + bb.w) * a;
        if (iblk == 0) {
            *(float4*)(ap + j * 64) = y;
        } else {
            float4 p = *(const float4*)(ap + j * 64);
            p.x += y.x; p.y += y.y; p.z += y.z; p.w += y.w;
            *(float4*)(ap + j * 64) = p;
        }
    }
}

// ---------------- i=2: attn + LN2 + fused final LN(accum + y2 + x3) ----------
extern "C" __global__ void __launch_bounds__(256)
attn_last(const unsigned short* __restrict__ q, const unsigned short* __restrict__ kf,
          const unsigned short* __restrict__ vf, const int* __restrict__ knn,
          const float* __restrict__ alpha, const float* __restrict__ lng,
          const float* __restrict__ lnb, const float* __restrict__ accum,
          const float* __restrict__ x3, const float* __restrict__ fng,
          const float* __restrict__ fnb, float* __restrict__ out) {
    const int tid = threadIdx.x;
    const int t = tid & 15;
    const int row = blockIdx.x * 16 + (tid >> 4);
    const int b = row / N_;
    const int n = row - b * N_;
    float qv[16], o[16];
    attn_core(q, kf, vf, knn, row, b, n, t, qv, o);

    // ---- LN2(o + Q) ----
    float s1 = 0.f, s2 = 0.f;
#pragma unroll
    for (int c = 0; c < 16; ++c) {
        o[c] += qv[c];
        s1 += o[c];
        s2 += o[c] * o[c];
    }
#pragma unroll
    for (int off = 1; off < 16; off <<= 1) {
        s1 += __shfl_xor(s1, off, 64);
        s2 += __shfl_xor(s2, off, 64);
    }
    const float mean = s1 * (1.f / C_);
    const float var = s2 * (1.f / C_) - mean * mean;
    const float rstd = rsqrtf(var + 1e-5f);

    // ---- r = accum + x3 + a2*LN2(o); reuse o[] as r[] ----
    const float a = alpha[row * 3 + 2];
    const float* gp = lng + 2 * C_ + t * 4;
    const float* bp = lnb + 2 * C_ + t * 4;
    const float* ap = accum + (size_t)row * C_ + t * 4;
    const float* xp = x3 + (size_t)row * C_ + t * 4;
    float u1 = 0.f, u2 = 0.f;
#pragma unroll
    for (int j = 0; j < 4; ++j) {
        float4 gg = *(const float4*)(gp + j * 64);
        float4 bb = *(const float4*)(bp + j * 64);
        float4 pa = *(const float4*)(ap + j * 64);
        float4 xv = *(const float4*)(xp + j * 64);
        o[j * 4 + 0] = pa.x + xv.x + ((o[j * 4 + 0] - mean) * rstd * gg.x + bb.x) * a;
        o[j * 4 + 1] = pa.y + xv.y + ((o[j * 4 + 1] - mean) * rstd * gg.y + bb.y) * a;
        o[j * 4 + 2] = pa.z + xv.z + ((o[j * 4 + 2] - mean) * rstd * gg.z + bb.z) * a;
        o[j * 4 + 3] = pa.w + xv.w + ((o[j * 4 + 3] - mean) * rstd * gg.w + bb.w) * a;
    }
#pragma unroll
    for (int c = 0; c < 16; ++c) {
        u1 += o[c];
        u2 += o[c] * o[c];
    }
#pragma unroll
    for (int off = 1; off < 16; off <<= 1) {
        u1 += __shfl_xor(u1, off, 64);
        u2 += __shfl_xor(u2, off, 64);
    }
    const float fmean = u1 * (1.f / C_);
    const float fvar = u2 * (1.f / C_) - fmean * fmean;
    const float frstd = rsqrtf(fvar + 1e-5f);

    const float* fgp = fng + t * 4;
    const float* fbp = fnb + t * 4;
    float* op = out + (size_t)row * C_ + t * 4;
#pragma unroll
    for (int j = 0; j < 4; ++j) {
        float4 gg = *(const float4*)(fgp + j * 64);
        float4 bb = *(const float4*)(fbp + j * 64);
        float4 y;
        y.x = (o[j * 4 + 0] - fmean) * frstd * gg.x + bb.x;
        y.y = (o[j * 4 + 1] - fmean) * frstd * gg.y + bb.y;
        y.z = (o[j * 4 + 2] - fmean) * frstd * gg.z + bb.z;
        y.w = (o[j * 4 + 3] - fmean) * frstd * gg.w + bb.w;
        *(float4*)(op + j * 64) = y;
    }
}

extern "C" void kernel_launch(void* const* d_in, const int* in_sizes, int n_in,
                              void* d_out, int out_size, void* d_ws, size_t ws_size,
                              hipStream_t stream) {
    const float* x0 = (const float*)d_in[0];
    const float* x1 = (const float*)d_in[1];
    const float* x2 = (const float*)d_in[2];
    const float* x3 = (const float*)d_in[3];
    const int* knn = (const int*)d_in[4];
    const float* Wq = (const float*)d_in[5];
    const float* bq = (const float*)d_in[6];
    const float* Wk = (const float*)d_in[7];
    const float* bk = (const float*)d_in[8];
    const float* Wv = (const float*)d_in[9];
    const float* bv = (const float*)d_in[10];
    const float* ln_g = (const float*)d_in[11];
    const float* ln_b = (const float*)d_in[12];
    const float* Wg1 = (const float*)d_in[13];
    const float* bg1 = (const float*)d_in[14];
    const float* Wg2 = (const float*)d_in[15];
    const float* bg2 = (const float*)d_in[16];
    const float* fn_g = (const float*)d_in[17];
    const float* fn_b = (const float*)d_in[18];
    float* out = (float*)d_out;

    unsigned char* w8 = (unsigned char*)d_ws;
    const size_t XBF = (size_t)MPAD * C_ * 2;        // 20,512,768 B
    const size_t HBF = (size_t)MPAD * H_ * 2;        // 10,256,384 B
    const size_t WBLOB = (size_t)3 * C_ * C_ * 2;    //    393,216 B
    const size_t WG1B = (size_t)H_ * C_ * 2;
    const size_t XE = (size_t)MPAD * C_;

    unsigned short* x3bf  = (unsigned short*)(w8);
    unsigned short* xqall = (unsigned short*)(w8 + XBF);        // 3 tensors
    unsigned short* qbf   = (unsigned short*)(w8 + 4 * XBF);
    unsigned short* kvbf  = (unsigned short*)(w8 + 5 * XBF);    // 6 tensors
    unsigned short* Hbf   = (unsigned short*)(w8 + 11 * XBF);
    unsigned short* wqbf  = (unsigned short*)(w8 + 11 * XBF + HBF);
    unsigned short* wkbf  = (unsigned short*)(w8 + 11 * XBF + HBF + WBLOB);
    unsigned short* wvbf  = (unsigned short*)(w8 + 11 * XBF + HBF + 2 * WBLOB);
    unsigned short* wg1bf = (unsigned short*)(w8 + 11 * XBF + HBF + 3 * WBLOB);
    float* alpha = (float*)(w8 + 11 * XBF + HBF + 3 * WBLOB + WG1B);

    const int xn4 = ROWS * C_ / 4;          // 2,560,000
    const int wn4 = 3 * C_ * C_ / 4;        // 49,152

    // conversions
    cvtx_kernel<<<dim3((xn4 + 255) / 256, 4), 256, 0, stream>>>(
        x3, x0, x1, x2, x3bf, xqall, xn4);
    cvtw_kernel<<<dim3((wn4 + 255) / 256, 4), 256, 0, stream>>>(
        Wq, Wk, Wv, Wg1, wqbf, wkbf, wvbf, wg1bf);

    // gate: H GEMM (own dispatch), then alpha
    gemm_h<<<dim3(MT), 256, 0, stream>>>(x3bf, wg1bf, bg1, Hbf);
    gate2_kernel<<<ROWS / 4, 256, 0, stream>>>(Hbf, Wg2, bg2, alpha);

    // merged KV GEMM: K0,V0,K1,V1,K2,V2 in one dispatch (A = x3 for all)
    gemm_kv<<<dim3(12, MT), 256, 0, stream>>>(x3bf, wkbf, wvbf, bk, bv, kvbf);

    for (int i = 0; i < 3; ++i) {
        gemm_q<<<dim3(MT, 2), 256, 0, stream>>>(
            xqall + (size_t)i * XE, wqbf + (size_t)i * C_ * C_, bq + i * C_, qbf);
        const unsigned short* kf = kvbf + (size_t)(2 * i) * XE;
        const unsigned short* vf = kvbf + (size_t)(2 * i + 1) * XE;
        if (i < 2) {
            attn_kernel<<<ROWS / 16, 256, 0, stream>>>(qbf, kf, vf, knn, alpha,
                                                       ln_g, ln_b, out, i);
        } else {
            attn_last<<<ROWS / 16, 256, 0, stream>>>(qbf, kf, vf, knn, alpha,
                                                     ln_g, ln_b, out, x3,
                                                     fn_g, fn_b, out);
        }
    }
}

// Round 10
// 623.028 us; speedup vs baseline: 1.0073x; 1.0073x over previous
//
#include <hip/hip_runtime.h>

#define B_ 2
#define N_ 20000
#define C_ 256
#define K_ 16
#define H_ 128
#define ROWS (B_ * N_)       // 40000
#define MT 313               // ceil(40000/128)
#define MPAD (MT * 128)      // 40064

typedef __attribute__((ext_vector_type(8))) short bf16x8;
typedef __attribute__((ext_vector_type(4))) float f32x4;

__device__ __forceinline__ float us2f(unsigned short u) {
    return __uint_as_float(((unsigned int)u) << 16);
}
__device__ __forceinline__ unsigned short f2us(float f) {
    unsigned int u = __float_as_uint(f);
    unsigned int r = (u + 0x7fffu + ((u >> 16) & 1u)) >> 16;
    return (unsigned short)r;
}
__device__ __forceinline__ float wred(float v) {
#pragma unroll
    for (int off = 32; off > 0; off >>= 1) v += __shfl_xor(v, off, 64);
    return v;
}
__device__ __forceinline__ void gld_lds16(const unsigned short* g, unsigned short* l) {
    __builtin_amdgcn_global_load_lds(
        (__attribute__((address_space(1))) void*)(g),
        (__attribute__((address_space(3))) void*)(l), 16, 0, 0);
}

// ---------------- fp32 -> bf16 convert (x3 only now) -------------------------
extern "C" __global__ void __launch_bounds__(256)
cvt_kernel(const float* __restrict__ src, unsigned short* __restrict__ dst, int n4) {
    int t = blockIdx.x * 256 + threadIdx.x;
    if (t >= n4) return;
    float4 v = ((const float4*)src)[t];
    ushort4 o;
    o.x = f2us(v.x); o.y = f2us(v.y); o.z = f2us(v.z); o.w = f2us(v.w);
    ((ushort4*)dst)[t] = o;
}

// ---------------- batched weight convert (4 tensors, one dispatch) -----------
extern "C" __global__ void __launch_bounds__(256)
cvtw_kernel(const float* __restrict__ s0, const float* __restrict__ s1,
            const float* __restrict__ s2, const float* __restrict__ s3,
            unsigned short* __restrict__ d0, unsigned short* __restrict__ d1,
            unsigned short* __restrict__ d2, unsigned short* __restrict__ d3) {
    const int y = blockIdx.y;
    const float* src = (y == 0) ? s0 : (y == 1 ? s1 : (y == 2 ? s2 : s3));
    unsigned short* dst = (y == 0) ? d0 : (y == 1 ? d1 : (y == 2 ? d2 : d3));
    const int n4 = (y < 3) ? (3 * C_ * C_ / 4) : (H_ * C_ / 4);
    int t = blockIdx.x * 256 + threadIdx.x;
    if (t >= n4) return;
    float4 v = ((const float4*)src)[t];
    ushort4 o;
    o.x = f2us(v.x); o.y = f2us(v.y); o.z = f2us(v.z); o.w = f2us(v.w);
    ((ushort4*)dst)[t] = o;
}

// ---------------- 128x128 MFMA tile body, BK=64, bf16 A (round-9 verified) ---
__device__ __forceinline__ void gemm_tile_body(
    const unsigned short* __restrict__ A, const unsigned short* __restrict__ W,
    const float* __restrict__ bias, unsigned short* __restrict__ O,
    const int m0, const int n0, const int ldo) {
    const int tid = threadIdx.x;
    const int w = tid >> 6, lane = tid & 63;
    const int l15 = lane & 15, l4 = lane >> 4;
    const int rowq = (w >> 1) * 64;
    const int colq = (w & 1) * 64;

    __shared__ unsigned short As[128 * 64];
    __shared__ unsigned short Bs[128 * 64];

    f32x4 acc[4][4] = {};

    const int srow = w * 8 + (lane >> 3);
    const int schunk = lane & 7;

    for (int k0 = 0; k0 < 256; k0 += 64) {
        __syncthreads();
#pragma unroll
        for (int issue = 0; issue < 4; ++issue) {
            const int lrow = issue * 32 + srow;
            const int sc = (schunk ^ ((lrow >> 1) & 7)) * 8;
            gld_lds16(A + (size_t)(m0 + lrow) * 256 + k0 + sc, As + issue * 2048 + w * 512);
            gld_lds16(W + (size_t)(n0 + lrow) * 256 + k0 + sc, Bs + issue * 2048 + w * 512);
        }
        __syncthreads();
#pragma unroll
        for (int ks = 0; ks < 2; ++ks) {
            bf16x8 a[4], b[4];
#pragma unroll
            for (int i = 0; i < 4; ++i) {
                const int ra = rowq + i * 16 + l15;
                const int ch = ((ks << 2) | l4) ^ ((ra >> 1) & 7);
                a[i] = *(const bf16x8*)&As[ra * 64 + ch * 8];
            }
#pragma unroll
            for (int j = 0; j < 4; ++j) {
                const int rb = colq + j * 16 + l15;
                const int ch = ((ks << 2) | l4) ^ ((rb >> 1) & 7);
                b[j] = *(const bf16x8*)&Bs[rb * 64 + ch * 8];
            }
#pragma unroll
            for (int i = 0; i < 4; ++i)
#pragma unroll
                for (int j = 0; j < 4; ++j)
                    acc[i][j] = __builtin_amdgcn_mfma_f32_16x16x32_bf16(b[j], a[i], acc[i][j], 0, 0, 0);
        }
    }

#pragma unroll
    for (int i = 0; i < 4; ++i) {
        const int grow = m0 + rowq + i * 16 + l15;
        if (grow < ROWS) {
#pragma unroll
            for (int j = 0; j < 4; ++j) {
                const int gcol = n0 + colq + j * 16 + l4 * 4;
                const float4 b4 = *(const float4*)&bias[gcol];
                uint2 pk;
                pk.x = (unsigned int)f2us(acc[i][j][0] + b4.x) |
                       ((unsigned int)f2us(acc[i][j][1] + b4.y) << 16);
                pk.y = (unsigned int)f2us(acc[i][j][2] + b4.z) |
                       ((unsigned int)f2us(acc[i][j][3] + b4.w) << 16);
                *(uint2*)&O[(size_t)grow * ldo + gcol] = pk;
            }
        }
    }
}

// ---------------- same body, A read directly from fp32 (fused convert) -------
// A-side staging: 16 threads/row x float4; convert -> swizzled ds_write (8B).
// Swizzle involution identical to read side: chunk ^= (row>>1)&7, 16B slots.
__device__ __forceinline__ void gemm_tile_body_f32a(
    const float* __restrict__ A, const unsigned short* __restrict__ W,
    const float* __restrict__ bias, unsigned short* __restrict__ O,
    const int m0, const int n0, const int ldo) {
    const int tid = threadIdx.x;
    const int w = tid >> 6, lane = tid & 63;
    const int l15 = lane & 15, l4 = lane >> 4;
    const int rowq = (w >> 1) * 64;
    const int colq = (w & 1) * 64;

    __shared__ unsigned short As[128 * 64];
    __shared__ unsigned short Bs[128 * 64];

    f32x4 acc[4][4] = {};

    const int srow = w * 8 + (lane >> 3);
    const int schunk = lane & 7;
    const int arow = tid >> 4;           // 0..15 (+issue*16)
    const int ac4 = (tid & 15) * 4;      // fp32 col offset within 64-wide K-step

    for (int k0 = 0; k0 < 256; k0 += 64) {
        float4 f4[8];
#pragma unroll
        for (int issue = 0; issue < 8; ++issue) {
            const int lrow = issue * 16 + arow;
            f4[issue] = *(const float4*)&A[(size_t)(m0 + lrow) * 256 + k0 + ac4];
        }
        __syncthreads();
#pragma unroll
        for (int issue = 0; issue < 4; ++issue) {
            const int lrow = issue * 32 + srow;
            const int sc = (schunk ^ ((lrow >> 1) & 7)) * 8;
            gld_lds16(W + (size_t)(n0 + lrow) * 256 + k0 + sc, Bs + issue * 2048 + w * 512);
        }
#pragma unroll
        for (int issue = 0; issue < 8; ++issue) {
            const int lrow = issue * 16 + arow;
            const int off = lrow * 64 + (((ac4 >> 3) ^ ((lrow >> 1) & 7)) << 3) + (ac4 & 7);
            uint2 pk;
            pk.x = (unsigned int)f2us(f4[issue].x) | ((unsigned int)f2us(f4[issue].y) << 16);
            pk.y = (unsigned int)f2us(f4[issue].z) | ((unsigned int)f2us(f4[issue].w) << 16);
            *(uint2*)&As[off] = pk;
        }
        __syncthreads();
#pragma unroll
        for (int ks = 0; ks < 2; ++ks) {
            bf16x8 a[4], b[4];
#pragma unroll
            for (int i = 0; i < 4; ++i) {
                const int ra = rowq + i * 16 + l15;
                const int ch = ((ks << 2) | l4) ^ ((ra >> 1) & 7);
                a[i] = *(const bf16x8*)&As[ra * 64 + ch * 8];
            }
#pragma unroll
            for (int j = 0; j < 4; ++j) {
                const int rb = colq + j * 16 + l15;
                const int ch = ((ks << 2) | l4) ^ ((rb >> 1) & 7);
                b[j] = *(const bf16x8*)&Bs[rb * 64 + ch * 8];
            }
#pragma unroll
            for (int i = 0; i < 4; ++i)
#pragma unroll
                for (int j = 0; j < 4; ++j)
                    acc[i][j] = __builtin_amdgcn_mfma_f32_16x16x32_bf16(b[j], a[i], acc[i][j], 0, 0, 0);
        }
    }

#pragma unroll
    for (int i = 0; i < 4; ++i) {
        const int grow = m0 + rowq + i * 16 + l15;
        if (grow < ROWS) {
#pragma unroll
            for (int j = 0; j < 4; ++j) {
                const int gcol = n0 + colq + j * 16 + l4 * 4;
                const float4 b4 = *(const float4*)&bias[gcol];
                uint2 pk;
                pk.x = (unsigned int)f2us(acc[i][j][0] + b4.x) |
                       ((unsigned int)f2us(acc[i][j][1] + b4.y) << 16);
                pk.y = (unsigned int)f2us(acc[i][j][2] + b4.z) |
                       ((unsigned int)f2us(acc[i][j][3] + b4.w) << 16);
                *(uint2*)&O[(size_t)grow * ldo + gcol] = pk;
            }
        }
    }
}

// ---------------- per-i KV GEMM: K_i,V_i (4 panels); A = x3bf ----------------
extern "C" __global__ void __launch_bounds__(256)
gemm_kvi(const unsigned short* __restrict__ x3bf,
         const unsigned short* __restrict__ wk, const unsigned short* __restrict__ wv,
         const float* __restrict__ bk, const float* __restrict__ bv,
         unsigned short* __restrict__ kv) {
    const int panel = blockIdx.x;
    const int zi = panel >> 1;           // 0=K, 1=V
    const unsigned short* W = zi ? wv : wk;
    const float* bias = zi ? bv : bk;
    unsigned short* O = kv + (size_t)zi * MPAD * C_;
    gemm_tile_body(x3bf, W, bias, O, blockIdx.y * 128, (panel & 1) * 128, C_);
}

// ---------------- per-i Q GEMM, A = fp32 xq[i] (fused convert) ---------------
extern "C" __global__ void __launch_bounds__(256)
gemm_q32(const float* __restrict__ xq, const unsigned short* __restrict__ wq,
         const float* __restrict__ bq, unsigned short* __restrict__ O) {
    gemm_tile_body_f32a(xq, wq, bq, O, blockIdx.y * 128, blockIdx.x * 128, C_);
}

// ---------------- gate GEMM: H = x3 @ Wg1^T + bg1 (128 cols) -----------------
extern "C" __global__ void __launch_bounds__(256)
gemm_h(const unsigned short* __restrict__ x3bf, const unsigned short* __restrict__ wg1,
       const float* __restrict__ bg1, unsigned short* __restrict__ Hout) {
    gemm_tile_body(x3bf, wg1, bg1, Hout, blockIdx.x * 128, 0, H_);
}

// ---------------- gate stage 2: alpha = softmax(relu(H)@Wg2^T + bg2) ---------
extern "C" __global__ void __launch_bounds__(256)
gate2_kernel(const unsigned short* __restrict__ Hbf, const float* __restrict__ Wg2,
             const float* __restrict__ bg2, float* __restrict__ alpha) {
    const int tid = threadIdx.x;
    const int w = tid >> 6, lane = tid & 63;
    const int row = blockIdx.x * 4 + w;
    const float h0 = fmaxf(us2f(Hbf[(size_t)row * H_ + lane]), 0.f);
    const float h1 = fmaxf(us2f(Hbf[(size_t)row * H_ + 64 + lane]), 0.f);
    float lg[3];
#pragma unroll
    for (int l = 0; l < 3; ++l) {
        const float* w2 = Wg2 + l * H_;
        lg[l] = wred(h0 * w2[lane] + h1 * w2[lane + 64]) + bg2[l];
    }
    float m = fmaxf(lg[0], fmaxf(lg[1], lg[2]));
    float e0 = expf(lg[0] - m), e1 = expf(lg[1] - m), e2 = expf(lg[2] - m);
    float inv = 1.f / (e0 + e1 + e2);
    if (lane == 0) {
        alpha[row * 3 + 0] = e0 * inv;
        alpha[row * 3 + 1] = e1 * inv;
        alpha[row * 3 + 2] = e2 * inv;
    }
}

// ---------------- attention core (round-0 proven body, 96 VGPR) --------------
__device__ __forceinline__ void attn_core(
    const unsigned short* __restrict__ q, const unsigned short* __restrict__ kf,
    const unsigned short* __restrict__ vf, const int* __restrict__ knn,
    const int row, const int b, const int n, const int t,
    float* __restrict__ qv, float* __restrict__ o) {
    const unsigned short* qp = q + (size_t)row * C_ + t * 4;
#pragma unroll
    for (int j = 0; j < 4; ++j) {
        ushort4 u = *(const ushort4*)(qp + j * 64);
        qv[j * 4 + 0] = us2f(u.x);
        qv[j * 4 + 1] = us2f(u.y);
        qv[j * 4 + 2] = us2f(u.z);
        qv[j * 4 + 3] = us2f(u.w);
    }

    int idxs[K_];
    float s[K_];
#pragma unroll
    for (int k = 0; k < K_; ++k) {
        idxs[k] = knn[n * K_ + k];
        const unsigned short* kp = kf + ((size_t)b * N_ + idxs[k]) * C_ + t * 4;
        float p = 0.f;
#pragma unroll
        for (int j = 0; j < 4; ++j) {
            ushort4 u = *(const ushort4*)(kp + j * 64);
            p += qv[j * 4 + 0] * us2f(u.x) + qv[j * 4 + 1] * us2f(u.y) +
                 qv[j * 4 + 2] * us2f(u.z) + qv[j * 4 + 3] * us2f(u.w);
        }
#pragma unroll
        for (int off = 1; off < 16; off <<= 1) p += __shfl_xor(p, off, 64);
        s[k] = p * 0.0625f;
    }

    float m = s[0];
#pragma unroll
    for (int k = 1; k < K_; ++k) m = fmaxf(m, s[k]);
    float sum = 0.f;
#pragma unroll
    for (int k = 0; k < K_; ++k) {
        s[k] = __expf(s[k] - m);
        sum += s[k];
    }
    const float inv = 1.f / sum;

#pragma unroll
    for (int c = 0; c < 16; ++c) o[c] = 0.f;
#pragma unroll
    for (int k = 0; k < K_; ++k) {
        const float a = s[k] * inv;
        const unsigned short* vp = vf + ((size_t)b * N_ + idxs[k]) * C_ + t * 4;
#pragma unroll
        for (int j = 0; j < 4; ++j) {
            ushort4 u = *(const ushort4*)(vp + j * 64);
            o[j * 4 + 0] += a * us2f(u.x);
            o[j * 4 + 1] += a * us2f(u.y);
            o[j * 4 + 2] += a * us2f(u.z);
            o[j * 4 + 3] += a * us2f(u.w);
        }
    }
}

// ---------------- i=0,1: attn + LN + alpha-weighted accumulate ---------------
extern "C" __global__ void __launch_bounds__(256)
attn_kernel(const unsigned short* __restrict__ q, const unsigned short* __restrict__ kf,
            const unsigned short* __restrict__ vf, const int* __restrict__ knn,
            const float* __restrict__ alpha, const float* __restrict__ lng,
            const float* __restrict__ lnb, float* __restrict__ accum, const int iblk) {
    const int tid = threadIdx.x;
    const int t = tid & 15;
    const int row = blockIdx.x * 16 + (tid >> 4);
    const int b = row / N_;
    const int n = row - b * N_;
    float qv[16], o[16];
    attn_core(q, kf, vf, knn, row, b, n, t, qv, o);

    float s1 = 0.f, s2 = 0.f;
#pragma unroll
    for (int c = 0; c < 16; ++c) {
        o[c] += qv[c];
        s1 += o[c];
        s2 += o[c] * o[c];
    }
#pragma unroll
    for (int off = 1; off < 16; off <<= 1) {
        s1 += __shfl_xor(s1, off, 64);
        s2 += __shfl_xor(s2, off, 64);
    }
    const float mean = s1 * (1.f / C_);
    const float var = s2 * (1.f / C_) - mean * mean;
    const float rstd = rsqrtf(var + 1e-5f);

    const float a = alpha[row * 3 + iblk];
    const float* gp = lng + iblk * C_ + t * 4;
    const float* bp = lnb + iblk * C_ + t * 4;
    float* ap = accum + (size_t)row * C_ + t * 4;
#pragma unroll
    for (int j = 0; j < 4; ++j) {
        float4 gg = *(const float4*)(gp + j * 64);
        float4 bb = *(const float4*)(bp + j * 64);
        float4 y;
        y.x = ((o[j * 4 + 0] - mean) * rstd * gg.x + bb.x) * a;
        y.y = ((o[j * 4 + 1] - mean) * rstd * gg.y + bb.y) * a;
        y.z = ((o[j * 4 + 2] - mean) * rstd * gg.z + bb.z) * a;
        y.w = ((o[j * 4 + 3] - mean) * rstd * gg.w + bb.w) * a;
        if (iblk == 0) {
            *(float4*)(ap + j * 64) = y;
        } else {
            float4 p = *(const float4*)(ap + j * 64);
            p.x += y.x; p.y += y.y; p.z += y.z; p.w += y.w;
            *(float4*)(ap + j * 64) = p;
        }
    }
}

// ---------------- i=2: attn + LN2 + fused final LN(accum + y2 + x3) ----------
extern "C" __global__ void __launch_bounds__(256)
attn_last(const unsigned short* __restrict__ q, const unsigned short* __restrict__ kf,
          const unsigned short* __restrict__ vf, const int* __restrict__ knn,
          const float* __restrict__ alpha, const float* __restrict__ lng,
          const float* __restrict__ lnb, const float* __restrict__ accum,
          const float* __restrict__ x3, const float* __restrict__ fng,
          const float* __restrict__ fnb, float* __restrict__ out) {
    const int tid = threadIdx.x;
    const int t = tid & 15;
    const int row = blockIdx.x * 16 + (tid >> 4);
    const int b = row / N_;
    const int n = row - b * N_;
    float qv[16], o[16];
    attn_core(q, kf, vf, knn, row, b, n, t, qv, o);

    float s1 = 0.f, s2 = 0.f;
#pragma unroll
    for (int c = 0; c < 16; ++c) {
        o[c] += qv[c];
        s1 += o[c];
        s2 += o[c] * o[c];
    }
#pragma unroll
    for (int off = 1; off < 16; off <<= 1) {
        s1 += __shfl_xor(s1, off, 64);
        s2 += __shfl_xor(s2, off, 64);
    }
    const float mean = s1 * (1.f / C_);
    const float var = s2 * (1.f / C_) - mean * mean;
    const float rstd = rsqrtf(var + 1e-5f);

    const float a = alpha[row * 3 + 2];
    const float* gp = lng + 2 * C_ + t * 4;
    const float* bp = lnb + 2 * C_ + t * 4;
    const float* ap = accum + (size_t)row * C_ + t * 4;
    const float* xp = x3 + (size_t)row * C_ + t * 4;
    float u1 = 0.f, u2 = 0.f;
#pragma unroll
    for (int j = 0; j < 4; ++j) {
        float4 gg = *(const float4*)(gp + j * 64);
        float4 bb = *(const float4*)(bp + j * 64);
        float4 pa = *(const float4*)(ap + j * 64);
        float4 xv = *(const float4*)(xp + j * 64);
        o[j * 4 + 0] = pa.x + xv.x + ((o[j * 4 + 0] - mean) * rstd * gg.x + bb.x) * a;
        o[j * 4 + 1] = pa.y + xv.y + ((o[j * 4 + 1] - mean) * rstd * gg.y + bb.y) * a;
        o[j * 4 + 2] = pa.z + xv.z + ((o[j * 4 + 2] - mean) * rstd * gg.z + bb.z) * a;
        o[j * 4 + 3] = pa.w + xv.w + ((o[j * 4 + 3] - mean) * rstd * gg.w + bb.w) * a;
    }
#pragma unroll
    for (int c = 0; c < 16; ++c) {
        u1 += o[c];
        u2 += o[c] * o[c];
    }
#pragma unroll
    for (int off = 1; off < 16; off <<= 1) {
        u1 += __shfl_xor(u1, off, 64);
        u2 += __shfl_xor(u2, off, 64);
    }
    const float fmean = u1 * (1.f / C_);
    const float fvar = u2 * (1.f / C_) - fmean * fmean;
    const float frstd = rsqrtf(fvar + 1e-5f);

    const float* fgp = fng + t * 4;
    const float* fbp = fnb + t * 4;
    float* op = out + (size_t)row * C_ + t * 4;
#pragma unroll
    for (int j = 0; j < 4; ++j) {
        float4 gg = *(const float4*)(fgp + j * 64);
        float4 bb = *(const float4*)(fbp + j * 64);
        float4 y;
        y.x = (o[j * 4 + 0] - fmean) * frstd * gg.x + bb.x;
        y.y = (o[j * 4 + 1] - fmean) * frstd * gg.y + bb.y;
        y.z = (o[j * 4 + 2] - fmean) * frstd * gg.z + bb.z;
        y.w = (o[j * 4 + 3] - fmean) * frstd * gg.w + bb.w;
        *(float4*)(op + j * 64) = y;
    }
}

extern "C" void kernel_launch(void* const* d_in, const int* in_sizes, int n_in,
                              void* d_out, int out_size, void* d_ws, size_t ws_size,
                              hipStream_t stream) {
    const float* x0 = (const float*)d_in[0];
    const float* x1 = (const float*)d_in[1];
    const float* x2 = (const float*)d_in[2];
    const float* x3 = (const float*)d_in[3];
    const int* knn = (const int*)d_in[4];
    const float* Wq = (const float*)d_in[5];
    const float* bq = (const float*)d_in[6];
    const float* Wk = (const float*)d_in[7];
    const float* bk = (const float*)d_in[8];
    const float* Wv = (const float*)d_in[9];
    const float* bv = (const float*)d_in[10];
    const float* ln_g = (const float*)d_in[11];
    const float* ln_b = (const float*)d_in[12];
    const float* Wg1 = (const float*)d_in[13];
    const float* bg1 = (const float*)d_in[14];
    const float* Wg2 = (const float*)d_in[15];
    const float* bg2 = (const float*)d_in[16];
    const float* fn_g = (const float*)d_in[17];
    const float* fn_b = (const float*)d_in[18];
    float* out = (float*)d_out;

    unsigned char* w8 = (unsigned char*)d_ws;
    const size_t XBF = (size_t)MPAD * C_ * 2;        // 20,512,768 B
    const size_t HBF = (size_t)MPAD * H_ * 2;        // 10,256,384 B
    const size_t WBLOB = (size_t)3 * C_ * C_ * 2;    //    393,216 B
    const size_t WG1B = (size_t)H_ * C_ * 2;
    const size_t XE = (size_t)MPAD * C_;

    unsigned short* x3bf  = (unsigned short*)(w8);
    unsigned short* qbf   = (unsigned short*)(w8 + XBF);
    unsigned short* kvbf  = (unsigned short*)(w8 + 2 * XBF);    // 2 tensors (K_i,V_i)
    unsigned short* Hbf   = (unsigned short*)(w8 + 4 * XBF);
    unsigned short* wqbf  = (unsigned short*)(w8 + 4 * XBF + HBF);
    unsigned short* wkbf  = (unsigned short*)(w8 + 4 * XBF + HBF + WBLOB);
    unsigned short* wvbf  = (unsigned short*)(w8 + 4 * XBF + HBF + 2 * WBLOB);
    unsigned short* wg1bf = (unsigned short*)(w8 + 4 * XBF + HBF + 3 * WBLOB);
    float* alpha = (float*)(w8 + 4 * XBF + HBF + 3 * WBLOB + WG1B);

    const int xn4 = ROWS * C_ / 4;          // 2,560,000
    const int wn4 = 3 * C_ * C_ / 4;        // 49,152
    const float* xq[3] = {x0, x1, x2};

    // conversions: x3 only + weights
    cvt_kernel<<<(xn4 + 255) / 256, 256, 0, stream>>>(x3, x3bf, xn4);
    cvtw_kernel<<<dim3((wn4 + 255) / 256, 4), 256, 0, stream>>>(
        Wq, Wk, Wv, Wg1, wqbf, wkbf, wvbf, wg1bf);

    // gate: H GEMM, then alpha
    gemm_h<<<dim3(MT), 256, 0, stream>>>(x3bf, wg1bf, bg1, Hbf);
    gate2_kernel<<<ROWS / 4, 256, 0, stream>>>(Hbf, Wg2, bg2, alpha);

    for (int i = 0; i < 3; ++i) {
        gemm_kvi<<<dim3(4, MT), 256, 0, stream>>>(
            x3bf, wkbf + (size_t)i * C_ * C_, wvbf + (size_t)i * C_ * C_,
            bk + i * C_, bv + i * C_, kvbf);
        gemm_q32<<<dim3(2, MT), 256, 0, stream>>>(
            xq[i], wqbf + (size_t)i * C_ * C_, bq + i * C_, qbf);
        if (i < 2) {
            attn_kernel<<<ROWS / 16, 256, 0, stream>>>(qbf, kvbf, kvbf + XE, knn,
                                                       alpha, ln_g, ln_b, out, i);
        } else {
            attn_last<<<ROWS / 16, 256, 0, stream>>>(qbf, kvbf, kvbf + XE, knn,
                                                     alpha, ln_g, ln_b, out, x3,
                                                     fn_g, fn_b, out);
        }
    }
}

// Round 11
// 601.099 us; speedup vs baseline: 1.0441x; 1.0365x over previous
//
#include <hip/hip_runtime.h>

#define B_ 2
#define N_ 20000
#define C_ 256
#define K_ 16
#define H_ 128
#define ROWS (B_ * N_)       // 40000
#define MT 313               // ceil(40000/128)
#define MPAD (MT * 128)      // 40064

typedef __attribute__((ext_vector_type(8))) short bf16x8;
typedef __attribute__((ext_vector_type(4))) float f32x4;

__device__ __forceinline__ float us2f(unsigned short u) {
    return __uint_as_float(((unsigned int)u) << 16);
}
__device__ __forceinline__ unsigned short f2us(float f) {
    unsigned int u = __float_as_uint(f);
    unsigned int r = (u + 0x7fffu + ((u >> 16) & 1u)) >> 16;
    return (unsigned short)r;
}
__device__ __forceinline__ float wred(float v) {
#pragma unroll
    for (int off = 32; off > 0; off >>= 1) v += __shfl_xor(v, off, 64);
    return v;
}
__device__ __forceinline__ void gld_lds16(const unsigned short* g, unsigned short* l) {
    __builtin_amdgcn_global_load_lds(
        (__attribute__((address_space(1))) void*)(g),
        (__attribute__((address_space(3))) void*)(l), 16, 0, 0);
}

// ---------------- fp32 -> bf16 convert (x3 only) -----------------------------
extern "C" __global__ void __launch_bounds__(256)
cvt_kernel(const float* __restrict__ src, unsigned short* __restrict__ dst, int n4) {
    int t = blockIdx.x * 256 + threadIdx.x;
    if (t >= n4) return;
    float4 v = ((const float4*)src)[t];
    ushort4 o;
    o.x = f2us(v.x); o.y = f2us(v.y); o.z = f2us(v.z); o.w = f2us(v.w);
    ((ushort4*)dst)[t] = o;
}

// ---------------- batched weight convert (4 tensors, one dispatch) -----------
extern "C" __global__ void __launch_bounds__(256)
cvtw_kernel(const float* __restrict__ s0, const float* __restrict__ s1,
            const float* __restrict__ s2, const float* __restrict__ s3,
            unsigned short* __restrict__ d0, unsigned short* __restrict__ d1,
            unsigned short* __restrict__ d2, unsigned short* __restrict__ d3) {
    const int y = blockIdx.y;
    const float* src = (y == 0) ? s0 : (y == 1 ? s1 : (y == 2 ? s2 : s3));
    unsigned short* dst = (y == 0) ? d0 : (y == 1 ? d1 : (y == 2 ? d2 : d3));
    const int n4 = (y < 3) ? (3 * C_ * C_ / 4) : (H_ * C_ / 4);
    int t = blockIdx.x * 256 + threadIdx.x;
    if (t >= n4) return;
    float4 v = ((const float4*)src)[t];
    ushort4 o;
    o.x = f2us(v.x); o.y = f2us(v.y); o.z = f2us(v.z); o.w = f2us(v.w);
    ((ushort4*)dst)[t] = o;
}

// ---------------- 128x128 MFMA tile body, BK=64, bf16 A (verified r9/r10) ----
// LDS buffers passed in so a multi-path kernel allocates them ONCE.
__device__ __forceinline__ void gemm_tile_body(
    unsigned short* __restrict__ As, unsigned short* __restrict__ Bs,
    const unsigned short* __restrict__ A, const unsigned short* __restrict__ W,
    const float* __restrict__ bias, unsigned short* __restrict__ O,
    const int m0, const int n0, const int ldo) {
    const int tid = threadIdx.x;
    const int w = tid >> 6, lane = tid & 63;
    const int l15 = lane & 15, l4 = lane >> 4;
    const int rowq = (w >> 1) * 64;
    const int colq = (w & 1) * 64;

    f32x4 acc[4][4] = {};

    const int srow = w * 8 + (lane >> 3);
    const int schunk = lane & 7;

    for (int k0 = 0; k0 < 256; k0 += 64) {
        __syncthreads();
#pragma unroll
        for (int issue = 0; issue < 4; ++issue) {
            const int lrow = issue * 32 + srow;
            const int sc = (schunk ^ ((lrow >> 1) & 7)) * 8;
            gld_lds16(A + (size_t)(m0 + lrow) * 256 + k0 + sc, As + issue * 2048 + w * 512);
            gld_lds16(W + (size_t)(n0 + lrow) * 256 + k0 + sc, Bs + issue * 2048 + w * 512);
        }
        __syncthreads();
#pragma unroll
        for (int ks = 0; ks < 2; ++ks) {
            bf16x8 a[4], b[4];
#pragma unroll
            for (int i = 0; i < 4; ++i) {
                const int ra = rowq + i * 16 + l15;
                const int ch = ((ks << 2) | l4) ^ ((ra >> 1) & 7);
                a[i] = *(const bf16x8*)&As[ra * 64 + ch * 8];
            }
#pragma unroll
            for (int j = 0; j < 4; ++j) {
                const int rb = colq + j * 16 + l15;
                const int ch = ((ks << 2) | l4) ^ ((rb >> 1) & 7);
                b[j] = *(const bf16x8*)&Bs[rb * 64 + ch * 8];
            }
#pragma unroll
            for (int i = 0; i < 4; ++i)
#pragma unroll
                for (int j = 0; j < 4; ++j)
                    acc[i][j] = __builtin_amdgcn_mfma_f32_16x16x32_bf16(b[j], a[i], acc[i][j], 0, 0, 0);
        }
    }

#pragma unroll
    for (int i = 0; i < 4; ++i) {
        const int grow = m0 + rowq + i * 16 + l15;
        if (grow < ROWS) {
#pragma unroll
            for (int j = 0; j < 4; ++j) {
                const int gcol = n0 + colq + j * 16 + l4 * 4;
                const float4 b4 = *(const float4*)&bias[gcol];
                uint2 pk;
                pk.x = (unsigned int)f2us(acc[i][j][0] + b4.x) |
                       ((unsigned int)f2us(acc[i][j][1] + b4.y) << 16);
                pk.y = (unsigned int)f2us(acc[i][j][2] + b4.z) |
                       ((unsigned int)f2us(acc[i][j][3] + b4.w) << 16);
                *(uint2*)&O[(size_t)grow * ldo + gcol] = pk;
            }
        }
    }
}

// ---------------- same body, A read directly from fp32 (verified r10) --------
__device__ __forceinline__ void gemm_tile_body_f32a(
    unsigned short* __restrict__ As, unsigned short* __restrict__ Bs,
    const float* __restrict__ A, const unsigned short* __restrict__ W,
    const float* __restrict__ bias, unsigned short* __restrict__ O,
    const int m0, const int n0, const int ldo) {
    const int tid = threadIdx.x;
    const int w = tid >> 6, lane = tid & 63;
    const int l15 = lane & 15, l4 = lane >> 4;
    const int rowq = (w >> 1) * 64;
    const int colq = (w & 1) * 64;

    f32x4 acc[4][4] = {};

    const int srow = w * 8 + (lane >> 3);
    const int schunk = lane & 7;
    const int arow = tid >> 4;
    const int ac4 = (tid & 15) * 4;

    for (int k0 = 0; k0 < 256; k0 += 64) {
        float4 f4[8];
#pragma unroll
        for (int issue = 0; issue < 8; ++issue) {
            const int lrow = issue * 16 + arow;
            f4[issue] = *(const float4*)&A[(size_t)(m0 + lrow) * 256 + k0 + ac4];
        }
        __syncthreads();
#pragma unroll
        for (int issue = 0; issue < 4; ++issue) {
            const int lrow = issue * 32 + srow;
            const int sc = (schunk ^ ((lrow >> 1) & 7)) * 8;
            gld_lds16(W + (size_t)(n0 + lrow) * 256 + k0 + sc, Bs + issue * 2048 + w * 512);
        }
#pragma unroll
        for (int issue = 0; issue < 8; ++issue) {
            const int lrow = issue * 16 + arow;
            const int off = lrow * 64 + (((ac4 >> 3) ^ ((lrow >> 1) & 7)) << 3) + (ac4 & 7);
            uint2 pk;
            pk.x = (unsigned int)f2us(f4[issue].x) | ((unsigned int)f2us(f4[issue].y) << 16);
            pk.y = (unsigned int)f2us(f4[issue].z) | ((unsigned int)f2us(f4[issue].w) << 16);
            *(uint2*)&As[off] = pk;
        }
        __syncthreads();
#pragma unroll
        for (int ks = 0; ks < 2; ++ks) {
            bf16x8 a[4], b[4];
#pragma unroll
            for (int i = 0; i < 4; ++i) {
                const int ra = rowq + i * 16 + l15;
                const int ch = ((ks << 2) | l4) ^ ((ra >> 1) & 7);
                a[i] = *(const bf16x8*)&As[ra * 64 + ch * 8];
            }
#pragma unroll
            for (int j = 0; j < 4; ++j) {
                const int rb = colq + j * 16 + l15;
                const int ch = ((ks << 2) | l4) ^ ((rb >> 1) & 7);
                b[j] = *(const bf16x8*)&Bs[rb * 64 + ch * 8];
            }
#pragma unroll
            for (int i = 0; i < 4; ++i)
#pragma unroll
                for (int j = 0; j < 4; ++j)
                    acc[i][j] = __builtin_amdgcn_mfma_f32_16x16x32_bf16(b[j], a[i], acc[i][j], 0, 0, 0);
        }
    }

#pragma unroll
    for (int i = 0; i < 4; ++i) {
        const int grow = m0 + rowq + i * 16 + l15;
        if (grow < ROWS) {
#pragma unroll
            for (int j = 0; j < 4; ++j) {
                const int gcol = n0 + colq + j * 16 + l4 * 4;
                const float4 b4 = *(const float4*)&bias[gcol];
                uint2 pk;
                pk.x = (unsigned int)f2us(acc[i][j][0] + b4.x) |
                       ((unsigned int)f2us(acc[i][j][1] + b4.y) << 16);
                pk.y = (unsigned int)f2us(acc[i][j][2] + b4.z) |
                       ((unsigned int)f2us(acc[i][j][3] + b4.w) << 16);
                *(uint2*)&O[(size_t)grow * ldo + gcol] = pk;
            }
        }
    }
}

// ---------------- merged per-i GEMM: K_i,V_i,Q_i (+ gate-H at i=0) -----------
// grid (7|6, MT): panel 0-3 = KV (zi=panel>>1, n0=(panel&1)*128, bf16 A=x3)
//                 panel 4-5 = Q  (n0=(panel-4)*128, fp32 A=xq[i])
//                 panel 6   = H  (i=0 only; 128 cols, ldo=H_)
extern "C" __global__ void __launch_bounds__(256)
gemm_qkv(const unsigned short* __restrict__ x3bf, const float* __restrict__ xq,
         const unsigned short* __restrict__ wk, const unsigned short* __restrict__ wv,
         const unsigned short* __restrict__ wq, const unsigned short* __restrict__ wg1,
         const float* __restrict__ bk, const float* __restrict__ bv,
         const float* __restrict__ bq, const float* __restrict__ bg1,
         unsigned short* __restrict__ kv, unsigned short* __restrict__ qo,
         unsigned short* __restrict__ Hout) {
    __shared__ unsigned short As[128 * 64];
    __shared__ unsigned short Bs[128 * 64];
    const int panel = blockIdx.x;
    const int m0 = blockIdx.y * 128;
    if (panel < 4) {
        const int zi = panel >> 1;           // 0=K, 1=V
        gemm_tile_body(As, Bs, x3bf, zi ? wv : wk, zi ? bv : bk,
                       kv + (size_t)zi * MPAD * C_, m0, (panel & 1) * 128, C_);
    } else if (panel < 6) {
        gemm_tile_body_f32a(As, Bs, xq, wq, bq, qo, m0, (panel - 4) * 128, C_);
    } else {
        gemm_tile_body(As, Bs, x3bf, wg1, bg1, Hout, m0, 0, H_);
    }
}

// ---------------- gate stage 2: alpha = softmax(relu(H)@Wg2^T + bg2) ---------
extern "C" __global__ void __launch_bounds__(256)
gate2_kernel(const unsigned short* __restrict__ Hbf, const float* __restrict__ Wg2,
             const float* __restrict__ bg2, float* __restrict__ alpha) {
    const int tid = threadIdx.x;
    const int w = tid >> 6, lane = tid & 63;
    const int row = blockIdx.x * 4 + w;
    const float h0 = fmaxf(us2f(Hbf[(size_t)row * H_ + lane]), 0.f);
    const float h1 = fmaxf(us2f(Hbf[(size_t)row * H_ + 64 + lane]), 0.f);
    float lg[3];
#pragma unroll
    for (int l = 0; l < 3; ++l) {
        const float* w2 = Wg2 + l * H_;
        lg[l] = wred(h0 * w2[lane] + h1 * w2[lane + 64]) + bg2[l];
    }
    float m = fmaxf(lg[0], fmaxf(lg[1], lg[2]));
    float e0 = expf(lg[0] - m), e1 = expf(lg[1] - m), e2 = expf(lg[2] - m);
    float inv = 1.f / (e0 + e1 + e2);
    if (lane == 0) {
        alpha[row * 3 + 0] = e0 * inv;
        alpha[row * 3 + 1] = e1 * inv;
        alpha[row * 3 + 2] = e2 * inv;
    }
}

// ---------------- attention core (round-0 proven body, 96 VGPR) --------------
__device__ __forceinline__ void attn_core(
    const unsigned short* __restrict__ q, const unsigned short* __restrict__ kf,
    const unsigned short* __restrict__ vf, const int* __restrict__ knn,
    const int row, const int b, const int n, const int t,
    float* __restrict__ qv, float* __restrict__ o) {
    const unsigned short* qp = q + (size_t)row * C_ + t * 4;
#pragma unroll
    for (int j = 0; j < 4; ++j) {
        ushort4 u = *(const ushort4*)(qp + j * 64);
        qv[j * 4 + 0] = us2f(u.x);
        qv[j * 4 + 1] = us2f(u.y);
        qv[j * 4 + 2] = us2f(u.z);
        qv[j * 4 + 3] = us2f(u.w);
    }

    int idxs[K_];
    float s[K_];
#pragma unroll
    for (int k = 0; k < K_; ++k) {
        idxs[k] = knn[n * K_ + k];
        const unsigned short* kp = kf + ((size_t)b * N_ + idxs[k]) * C_ + t * 4;
        float p = 0.f;
#pragma unroll
        for (int j = 0; j < 4; ++j) {
            ushort4 u = *(const ushort4*)(kp + j * 64);
            p += qv[j * 4 + 0] * us2f(u.x) + qv[j * 4 + 1] * us2f(u.y) +
                 qv[j * 4 + 2] * us2f(u.z) + qv[j * 4 + 3] * us2f(u.w);
        }
#pragma unroll
        for (int off = 1; off < 16; off <<= 1) p += __shfl_xor(p, off, 64);
        s[k] = p * 0.0625f;
    }

    float m = s[0];
#pragma unroll
    for (int k = 1; k < K_; ++k) m = fmaxf(m, s[k]);
    float sum = 0.f;
#pragma unroll
    for (int k = 0; k < K_; ++k) {
        s[k] = __expf(s[k] - m);
        sum += s[k];
    }
    const float inv = 1.f / sum;

#pragma unroll
    for (int c = 0; c < 16; ++c) o[c] = 0.f;
#pragma unroll
    for (int k = 0; k < K_; ++k) {
        const float a = s[k] * inv;
        const unsigned short* vp = vf + ((size_t)b * N_ + idxs[k]) * C_ + t * 4;
#pragma unroll
        for (int j = 0; j < 4; ++j) {
            ushort4 u = *(const ushort4*)(vp + j * 64);
            o[j * 4 + 0] += a * us2f(u.x);
            o[j * 4 + 1] += a * us2f(u.y);
            o[j * 4 + 2] += a * us2f(u.z);
            o[j * 4 + 3] += a * us2f(u.w);
        }
    }
}

// ---------------- i=0,1: attn + LN + alpha-weighted accumulate ---------------
extern "C" __global__ void __launch_bounds__(256)
attn_kernel(const unsigned short* __restrict__ q, const unsigned short* __restrict__ kf,
            const unsigned short* __restrict__ vf, const int* __restrict__ knn,
            const float* __restrict__ alpha, const float* __restrict__ lng,
            const float* __restrict__ lnb, float* __restrict__ accum, const int iblk) {
    const int tid = threadIdx.x;
    const int t = tid & 15;
    const int row = blockIdx.x * 16 + (tid >> 4);
    const int b = row / N_;
    const int n = row - b * N_;
    float qv[16], o[16];
    attn_core(q, kf, vf, knn, row, b, n, t, qv, o);

    float s1 = 0.f, s2 = 0.f;
#pragma unroll
    for (int c = 0; c < 16; ++c) {
        o[c] += qv[c];
        s1 += o[c];
        s2 += o[c] * o[c];
    }
#pragma unroll
    for (int off = 1; off < 16; off <<= 1) {
        s1 += __shfl_xor(s1, off, 64);
        s2 += __shfl_xor(s2, off, 64);
    }
    const float mean = s1 * (1.f / C_);
    const float var = s2 * (1.f / C_) - mean * mean;
    const float rstd = rsqrtf(var + 1e-5f);

    const float a = alpha[row * 3 + iblk];
    const float* gp = lng + iblk * C_ + t * 4;
    const float* bp = lnb + iblk * C_ + t * 4;
    float* ap = accum + (size_t)row * C_ + t * 4;
#pragma unroll
    for (int j = 0; j < 4; ++j) {
        float4 gg = *(const float4*)(gp + j * 64);
        float4 bb = *(const float4*)(bp + j * 64);
        float4 y;
        y.x = ((o[j * 4 + 0] - mean) * rstd * gg.x + bb.x) * a;
        y.y = ((o[j * 4 + 1] - mean) * rstd * gg.y + bb.y) * a;
        y.z = ((o[j * 4 + 2] - mean) * rstd * gg.z + bb.z) * a;
        y.w = ((o[j * 4 + 3] - mean) * rstd * gg.w + bb.w) * a;
        if (iblk == 0) {
            *(float4*)(ap + j * 64) = y;
        } else {
            float4 p = *(const float4*)(ap + j * 64);
            p.x += y.x; p.y += y.y; p.z += y.z; p.w += y.w;
            *(float4*)(ap + j * 64) = p;
        }
    }
}

// ---------------- i=2: attn + LN2 + fused final LN(accum + y2 + x3) ----------
extern "C" __global__ void __launch_bounds__(256)
attn_last(const unsigned short* __restrict__ q, const unsigned short* __restrict__ kf,
          const unsigned short* __restrict__ vf, const int* __restrict__ knn,
          const float* __restrict__ alpha, const float* __restrict__ lng,
          const float* __restrict__ lnb, const float* __restrict__ accum,
          const float* __restrict__ x3, const float* __restrict__ fng,
          const float* __restrict__ fnb, float* __restrict__ out) {
    const int tid = threadIdx.x;
    const int t = tid & 15;
    const int row = blockIdx.x * 16 + (tid >> 4);
    const int b = row / N_;
    const int n = row - b * N_;
    float qv[16], o[16];
    attn_core(q, kf, vf, knn, row, b, n, t, qv, o);

    float s1 = 0.f, s2 = 0.f;
#pragma unroll
    for (int c = 0; c < 16; ++c) {
        o[c] += qv[c];
        s1 += o[c];
        s2 += o[c] * o[c];
    }
#pragma unroll
    for (int off = 1; off < 16; off <<= 1) {
        s1 += __shfl_xor(s1, off, 64);
        s2 += __shfl_xor(s2, off, 64);
    }
    const float mean = s1 * (1.f / C_);
    const float var = s2 * (1.f / C_) - mean * mean;
    const float rstd = rsqrtf(var + 1e-5f);

    const float a = alpha[row * 3 + 2];
    const float* gp = lng + 2 * C_ + t * 4;
    const float* bp = lnb + 2 * C_ + t * 4;
    const float* ap = accum + (size_t)row * C_ + t * 4;
    const float* xp = x3 + (size_t)row * C_ + t * 4;
    float u1 = 0.f, u2 = 0.f;
#pragma unroll
    for (int j = 0; j < 4; ++j) {
        float4 gg = *(const float4*)(gp + j * 64);
        float4 bb = *(const float4*)(bp + j * 64);
        float4 pa = *(const float4*)(ap + j * 64);
        float4 xv = *(const float4*)(xp + j * 64);
        o[j * 4 + 0] = pa.x + xv.x + ((o[j * 4 + 0] - mean) * rstd * gg.x + bb.x) * a;
        o[j * 4 + 1] = pa.y + xv.y + ((o[j * 4 + 1] - mean) * rstd * gg.y + bb.y) * a;
        o[j * 4 + 2] = pa.z + xv.z + ((o[j * 4 + 2] - mean) * rstd * gg.z + bb.z) * a;
        o[j * 4 + 3] = pa.w + xv.w + ((o[j * 4 + 3] - mean) * rstd * gg.w + bb.w) * a;
    }
#pragma unroll
    for (int c = 0; c < 16; ++c) {
        u1 += o[c];
        u2 += o[c] * o[c];
    }
#pragma unroll
    for (int off = 1; off < 16; off <<= 1) {
        u1 += __shfl_xor(u1, off, 64);
        u2 += __shfl_xor(u2, off, 64);
    }
    const float fmean = u1 * (1.f / C_);
    const float fvar = u2 * (1.f / C_) - fmean * fmean;
    const float frstd = rsqrtf(fvar + 1e-5f);

    const float* fgp = fng + t * 4;
    const float* fbp = fnb + t * 4;
    float* op = out + (size_t)row * C_ + t * 4;
#pragma unroll
    for (int j = 0; j < 4; ++j) {
        float4 gg = *(const float4*)(fgp + j * 64);
        float4 bb = *(const float4*)(fbp + j * 64);
        float4 y;
        y.x = (o[j * 4 + 0] - fmean) * frstd * gg.x + bb.x;
        y.y = (o[j * 4 + 1] - fmean) * frstd * gg.y + bb.y;
        y.z = (o[j * 4 + 2] - fmean) * frstd * gg.z + bb.z;
        y.w = (o[j * 4 + 3] - fmean) * frstd * gg.w + bb.w;
        *(float4*)(op + j * 64) = y;
    }
}

extern "C" void kernel_launch(void* const* d_in, const int* in_sizes, int n_in,
                              void* d_out, int out_size, void* d_ws, size_t ws_size,
                              hipStream_t stream) {
    const float* x0 = (const float*)d_in[0];
    const float* x1 = (const float*)d_in[1];
    const float* x2 = (const float*)d_in[2];
    const float* x3 = (const float*)d_in[3];
    const int* knn = (const int*)d_in[4];
    const float* Wq = (const float*)d_in[5];
    const float* bq = (const float*)d_in[6];
    const float* Wk = (const float*)d_in[7];
    const float* bk = (const float*)d_in[8];
    const float* Wv = (const float*)d_in[9];
    const float* bv = (const float*)d_in[10];
    const float* ln_g = (const float*)d_in[11];
    const float* ln_b = (const float*)d_in[12];
    const float* Wg1 = (const float*)d_in[13];
    const float* bg1 = (const float*)d_in[14];
    const float* Wg2 = (const float*)d_in[15];
    const float* bg2 = (const float*)d_in[16];
    const float* fn_g = (const float*)d_in[17];
    const float* fn_b = (const float*)d_in[18];
    float* out = (float*)d_out;

    unsigned char* w8 = (unsigned char*)d_ws;
    const size_t XBF = (size_t)MPAD * C_ * 2;        // 20,512,768 B
    const size_t HBF = (size_t)MPAD * H_ * 2;        // 10,256,384 B
    const size_t WBLOB = (size_t)3 * C_ * C_ * 2;    //    393,216 B
    const size_t WG1B = (size_t)H_ * C_ * 2;
    const size_t XE = (size_t)MPAD * C_;

    unsigned short* x3bf  = (unsigned short*)(w8);
    unsigned short* qbf   = (unsigned short*)(w8 + XBF);
    unsigned short* kvbf  = (unsigned short*)(w8 + 2 * XBF);    // 2 tensors (K_i,V_i)
    unsigned short* Hbf   = (unsigned short*)(w8 + 4 * XBF);
    unsigned short* wqbf  = (unsigned short*)(w8 + 4 * XBF + HBF);
    unsigned short* wkbf  = (unsigned short*)(w8 + 4 * XBF + HBF + WBLOB);
    unsigned short* wvbf  = (unsigned short*)(w8 + 4 * XBF + HBF + 2 * WBLOB);
    unsigned short* wg1bf = (unsigned short*)(w8 + 4 * XBF + HBF + 3 * WBLOB);
    float* alpha = (float*)(w8 + 4 * XBF + HBF + 3 * WBLOB + WG1B);

    const int xn4 = ROWS * C_ / 4;          // 2,560,000
    const int wn4 = 3 * C_ * C_ / 4;        // 49,152
    const float* xq[3] = {x0, x1, x2};

    // conversions: x3 + weights
    cvt_kernel<<<(xn4 + 255) / 256, 256, 0, stream>>>(x3, x3bf, xn4);
    cvtw_kernel<<<dim3((wn4 + 255) / 256, 4), 256, 0, stream>>>(
        Wq, Wk, Wv, Wg1, wqbf, wkbf, wvbf, wg1bf);

    for (int i = 0; i < 3; ++i) {
        // merged K/V/Q (+H at i=0) GEMM for this block
        gemm_qkv<<<dim3(i == 0 ? 7 : 6, MT), 256, 0, stream>>>(
            x3bf, xq[i],
            wkbf + (size_t)i * C_ * C_, wvbf + (size_t)i * C_ * C_,
            wqbf + (size_t)i * C_ * C_, wg1bf,
            bk + i * C_, bv + i * C_, bq + i * C_, bg1,
            kvbf, qbf, Hbf);
        if (i == 0) {
            gate2_kernel<<<ROWS / 4, 256, 0, stream>>>(Hbf, Wg2, bg2, alpha);
        }
        if (i < 2) {
            attn_kernel<<<ROWS / 16, 256, 0, stream>>>(qbf, kvbf, kvbf + XE, knn,
                                                       alpha, ln_g, ln_b, out, i);
        } else {
            attn_last<<<ROWS / 16, 256, 0, stream>>>(qbf, kvbf, kvbf + XE, knn,
                                                     alpha, ln_g, ln_b, out, x3,
                                                     fn_g, fn_b, out);
        }
    }
}